// Round 1
// baseline (561.498 us; speedup 1.0000x reference)
//
#include <hip/hip_runtime.h>

#define NEGV (-1e30f)
#define EPSV (1e-7f)

constexpr int Tdim = 1024;
constexpr int Kdim = 128;
constexpr int Ldim = 64;

__device__ __forceinline__ float lse2(float a, float b) {
    float m = fmaxf(a, b);
    return m + __logf(__expf(a - m) + __expf(b - m));
}
__device__ __forceinline__ float lse3(float a, float b, float c) {
    float m = fmaxf(fmaxf(a, b), c);
    return m + __logf(__expf(a - m) + __expf(b - m) + __expf(c - m));
}

__global__ __launch_bounds__(64) void ctc_fwd_kernel(
    const int* __restrict__ y_true,      // (B, 64)
    const float* __restrict__ y_pred,    // (B, T, K)
    const int* __restrict__ in_len,      // (B, 1)
    const int* __restrict__ lab_len,     // (B, 1)
    float* __restrict__ out)             // (B, 1)
{
    const int b = blockIdx.x;
    const int lane = threadIdx.x;

    const float* yp  = y_pred + (size_t)b * Tdim * Kdim;
    const int lab = y_true[b * Ldim + lane];          // labels are 0..126, never blank
    const int lab_prev = __shfl_up(lab, 1, 64);
    const bool skip = (lane > 0) && (lab != Kdim - 1) && (lab != lab_prev);
    const int steps = in_len[b];                      // 512..1024

    const float* ypl = yp + lab;          // per-lane gather base
    const float* ypb = yp + (Kdim - 1);   // wave-uniform blank base

    // lane i holds alpha[2i] (a_e), alpha[2i+1] (a_o); lane 63 also alpha[128] (a_l)
    float a_e = (lane == 0) ? 0.0f : NEGV;
    float a_o = NEGV;
    float a_l = NEGV;

    constexpr int PF = 16;                // prefetch depth (static ring indices)
    float pl[PF], pb[PF];
    #pragma unroll
    for (int u = 0; u < PF; ++u) {
        if (u < steps) { pl[u] = ypl[u * Kdim]; pb[u] = ypb[u * Kdim]; }
    }

    for (int tb = 0; tb < steps; tb += PF) {
        #pragma unroll
        for (int u = 0; u < PF; ++u) {
            const int t = tb + u;
            if (t < steps) {                          // wave-uniform branch
                const float lp_lab = __logf(pl[u] + EPSV);
                const float lp_b   = __logf(pb[u] + EPSV);
                const int tn = t + PF;
                if (tn < steps) {                     // refill ring slot early
                    pl[u] = ypl[tn * Kdim];
                    pb[u] = ypb[tn * Kdim];
                }
                float p_o = __shfl_up(a_o, 1, 64);    // alpha[2i-1]
                if (lane == 0) p_o = NEGV;
                const float ne = lp_b   + lse2(a_e, p_o);
                const float no = lp_lab + lse3(a_o, a_e, skip ? p_o : NEGV);
                const float nl = lp_b   + lse2(a_l, a_o);
                a_e = ne; a_o = no; a_l = nl;
            }
        }
    }

    __shared__ float alpha_s[130];
    alpha_s[2 * lane]     = a_e;
    alpha_s[2 * lane + 1] = a_o;
    if (lane == 63) alpha_s[128] = a_l;
    __syncthreads();

    if (lane == 0) {
        const int ll = lab_len[b];
        const int i1 = 2 * ll;
        const int i2 = (i1 - 1 > 0) ? (i1 - 1) : 0;
        const float e1 = alpha_s[i1];
        const float e2 = alpha_s[i2];
        const float m = fmaxf(e1, e2);
        out[b] = -(m + __logf(__expf(e1 - m) + __expf(e2 - m)));
    }
}

extern "C" void kernel_launch(void* const* d_in, const int* in_sizes, int n_in,
                              void* d_out, int out_size, void* d_ws, size_t ws_size,
                              hipStream_t stream) {
    const int*   y_true   = (const int*)d_in[0];
    const float* y_pred   = (const float*)d_in[1];
    const int*   in_len   = (const int*)d_in[2];
    const int*   lab_len  = (const int*)d_in[3];
    float* out = (float*)d_out;

    const int B = in_sizes[0] / Ldim;   // 512
    ctc_fwd_kernel<<<B, 64, 0, stream>>>(y_true, y_pred, in_len, lab_len, out);
}

// Round 2
// 403.021 us; speedup vs baseline: 1.3932x; 1.3932x over previous
//
#include <hip/hip_runtime.h>

#define NEGV (-1e30f)
#define EPSV (1e-7f)
#define LN2F (0.69314718055994531f)

constexpr int Tdim = 1024;
constexpr int Kdim = 128;
constexpr int Ldim = 64;

// base-2 logsumexp helpers (v_log_f32 / v_exp_f32 are natively base-2)
__device__ __forceinline__ float lse2_b2(float a, float b) {
    float m = fmaxf(a, b);
    return m + __log2f(exp2f(a - m) + exp2f(b - m));
}
__device__ __forceinline__ float lse3_b2(float a, float b, float c) {
    float m = fmaxf(fmaxf(a, b), c);
    return m + __log2f(exp2f(a - m) + exp2f(b - m) + exp2f(c - m));
}

__global__ __launch_bounds__(64) void ctc_fwd_kernel(
    const int* __restrict__ y_true,      // (B, 64)
    const float* __restrict__ y_pred,    // (B, T, K)
    const int* __restrict__ in_len,      // (B, 1)
    const int* __restrict__ lab_len,     // (B, 1)
    float* __restrict__ out)             // (B, 1)
{
    const int b = blockIdx.x;
    const int lane = threadIdx.x;

    const float* yp  = y_pred + (size_t)b * Tdim * Kdim;
    const int lab = y_true[b * Ldim + lane];          // labels 0..126 (never blank)
    const int lab_prev = __shfl_up(lab, 1, 64);
    const bool skip = (lane > 0) && (lab != Kdim - 1) && (lab != lab_prev);
    const int steps = in_len[b];                      // 512..1024 (>= PF guaranteed)

    const float* ypl = yp + lab;          // per-lane gather base (label prob)
    const float* ypb = yp + (Kdim - 1);   // wave-uniform blank base

    // lane i holds alpha2[2i] (a_e), alpha2[2i+1] (a_o); lane 63 also alpha2[128] (a_l)
    // (alpha2 = alpha / ln2, i.e. base-2 log domain)
    float a_e = (lane == 0) ? 0.0f : NEGV;
    float a_o = NEGV;
    float a_l = NEGV;

    constexpr int PF = 32;                // prefetch depth; ring lives in VGPRs
    float pl[PF], pb[PF];

    // initial fill: t = 0..PF-1, always < steps (steps >= 512), unconditional
    #pragma unroll
    for (int u = 0; u < PF; ++u) {
        pl[u] = ypl[u * Kdim];
        pb[u] = ypb[u * Kdim];
    }

    const int steps_full = steps & ~(PF - 1);   // >= 512, multiple of PF

    for (int tb = 0; tb < steps_full; tb += PF) {
        #pragma unroll
        for (int u = 0; u < PF; ++u) {
            const float vl = pl[u];               // value loaded PF steps ago
            const float vb = pb[u];
            // refill ring slot immediately (issue early, consume PF steps later);
            // clamp to last row: always in-bounds, value unused when t >= steps
            int tn = tb + PF + u;
            tn = (tn > Tdim - 1) ? (Tdim - 1) : tn;
            pl[u] = ypl[tn * Kdim];
            pb[u] = ypb[tn * Kdim];

            const float lp_lab = __log2f(vl + EPSV);   // off the serial chain
            const float lp_b   = __log2f(vb + EPSV);

            float p_o = __shfl_up(a_o, 1, 64);         // alpha2[2i-1]
            p_o = (lane == 0) ? NEGV : p_o;
            const float ne = lp_b   + lse2_b2(a_e, p_o);
            const float no = lp_lab + lse3_b2(a_o, a_e, skip ? p_o : NEGV);
            const float nl = lp_b   + lse2_b2(a_l, a_o);
            a_e = ne; a_o = no; a_l = nl;
        }
    }

    // tail: up to PF-1 steps, wave-uniform guard, ring slots already loaded
    #pragma unroll
    for (int u = 0; u < PF; ++u) {
        if (steps_full + u < steps) {
            const float lp_lab = __log2f(pl[u] + EPSV);
            const float lp_b   = __log2f(pb[u] + EPSV);
            float p_o = __shfl_up(a_o, 1, 64);
            p_o = (lane == 0) ? NEGV : p_o;
            const float ne = lp_b   + lse2_b2(a_e, p_o);
            const float no = lp_lab + lse3_b2(a_o, a_e, skip ? p_o : NEGV);
            const float nl = lp_b   + lse2_b2(a_l, a_o);
            a_e = ne; a_o = no; a_l = nl;
        }
    }

    __shared__ float alpha_s[130];
    alpha_s[2 * lane]     = a_e;
    alpha_s[2 * lane + 1] = a_o;
    if (lane == 63) alpha_s[128] = a_l;
    __syncthreads();

    if (lane == 0) {
        const int ll = lab_len[b];
        const int i1 = 2 * ll;
        const int i2 = (i1 - 1 > 0) ? (i1 - 1) : 0;
        const float e1 = alpha_s[i1];
        const float e2 = alpha_s[i2];
        // loss = -ln(2) * lse2_base2(e1, e2)
        out[b] = -LN2F * lse2_b2(e1, e2);
    }
}

extern "C" void kernel_launch(void* const* d_in, const int* in_sizes, int n_in,
                              void* d_out, int out_size, void* d_ws, size_t ws_size,
                              hipStream_t stream) {
    const int*   y_true   = (const int*)d_in[0];
    const float* y_pred   = (const float*)d_in[1];
    const int*   in_len   = (const int*)d_in[2];
    const int*   lab_len  = (const int*)d_in[3];
    float* out = (float*)d_out;

    const int B = in_sizes[0] / Ldim;   // 512
    ctc_fwd_kernel<<<B, 64, 0, stream>>>(y_true, y_pred, in_len, lab_len, out);
}

// Round 4
// 402.918 us; speedup vs baseline: 1.3936x; 1.0003x over previous
//
#include <hip/hip_runtime.h>

#define NEGV (-1e30f)
#define EPSV (1e-7f)
#define LN2F (0.69314718055994531f)

constexpr int Tdim = 1024;
constexpr int Kdim = 128;
constexpr int Ldim = 64;

// base-2 logsumexp helpers (v_log_f32 / v_exp_f32 are natively base-2)
__device__ __forceinline__ float lse2_b2(float a, float b) {
    float m = fmaxf(a, b);
    return m + __log2f(exp2f(a - m) + exp2f(b - m));
}
__device__ __forceinline__ float lse3_b2(float a, float b, float c) {
    float m = fmaxf(fmaxf(a, b), c);
    return m + __log2f(exp2f(a - m) + exp2f(b - m) + exp2f(c - m));
}

// __launch_bounds__(64, 1): min-waves-per-EU = 1 lifts the scheduler's
// occupancy-driven VGPR cap (64-thread block with default target was capped
// at 32 VGPRs -> R1/R2's prefetch ring was squeezed out and loads were
// serialized against the dependence chain). We run 512 waves total (2/CU);
// occupancy is structurally irrelevant, register budget is not.
__global__ __launch_bounds__(64, 1) void ctc_fwd_kernel(
    const int* __restrict__ y_true,      // (B, 64)
    const float* __restrict__ y_pred,    // (B, T, K)
    const int* __restrict__ in_len,      // (B, 1)
    const int* __restrict__ lab_len,     // (B, 1)
    float* __restrict__ out)             // (B, 1)
{
    const int b = blockIdx.x;
    const int lane = threadIdx.x;

    const float* yp  = y_pred + (size_t)b * Tdim * Kdim;
    const int lab = y_true[b * Ldim + lane];          // labels 0..126 (never blank)
    const int lab_prev = __shfl_up(lab, 1, 64);
    const bool skip = (lane > 0) && (lab != Kdim - 1) && (lab != lab_prev);
    const int steps = in_len[b];                      // 512..1024 (>= PF guaranteed)

    const float* ypl = yp + lab;          // per-lane gather base (label prob)
    const float* ypb = yp + (Kdim - 1);   // wave-uniform blank base

    // lane i holds alpha2[2i] (a_e), alpha2[2i+1] (a_o); lane 63 also alpha2[128]
    // (alpha2 = alpha / ln2, i.e. base-2 log domain)
    float a_e = (lane == 0) ? 0.0f : NEGV;
    float a_o = NEGV;
    float a_l = NEGV;

    constexpr int PF = 32;                // prefetch depth; ring lives in VGPRs
    float pl[PF], pb[PF];

    // initial fill: t = 0..PF-1, always < steps (steps >= 512), unconditional
    #pragma unroll
    for (int u = 0; u < PF; ++u) {
        pl[u] = ypl[u * Kdim];
        pb[u] = ypb[u * Kdim];
    }

    const int steps_full = steps & ~(PF - 1);   // >= 512, multiple of PF

    for (int tb = 0; tb < steps_full; tb += PF) {
        #pragma unroll
        for (int u = 0; u < PF; ++u) {
            const float vl = pl[u];               // value loaded PF steps ago
            const float vb = pb[u];
            // refill ring slot immediately (issue early, consume PF steps later);
            // clamp to last row: always in-bounds, value unused when t >= steps
            int tn = tb + PF + u;
            tn = (tn > Tdim - 1) ? (Tdim - 1) : tn;
            pl[u] = ypl[tn * Kdim];
            pb[u] = ypb[tn * Kdim];

            const float lp_lab = __log2f(vl + EPSV);   // off the serial chain
            const float lp_b   = __log2f(vb + EPSV);

            float p_o = __shfl_up(a_o, 1, 64);         // alpha2[2i-1]
            p_o = (lane == 0) ? NEGV : p_o;
            const float ne = lp_b   + lse2_b2(a_e, p_o);
            const float no = lp_lab + lse3_b2(a_o, a_e, skip ? p_o : NEGV);
            const float nl = lp_b   + lse2_b2(a_l, a_o);
            a_e = ne; a_o = no; a_l = nl;
        }
    }

    // tail: up to PF-1 steps, wave-uniform guard, ring slots already loaded
    #pragma unroll
    for (int u = 0; u < PF; ++u) {
        if (steps_full + u < steps) {
            const float lp_lab = __log2f(pl[u] + EPSV);
            const float lp_b   = __log2f(pb[u] + EPSV);
            float p_o = __shfl_up(a_o, 1, 64);
            p_o = (lane == 0) ? NEGV : p_o;
            const float ne = lp_b   + lse2_b2(a_e, p_o);
            const float no = lp_lab + lse3_b2(a_o, a_e, skip ? p_o : NEGV);
            const float nl = lp_b   + lse2_b2(a_l, a_o);
            a_e = ne; a_o = no; a_l = nl;
        }
    }

    __shared__ float alpha_s[130];
    alpha_s[2 * lane]     = a_e;
    alpha_s[2 * lane + 1] = a_o;
    if (lane == 63) alpha_s[128] = a_l;
    __syncthreads();

    if (lane == 0) {
        const int ll = lab_len[b];
        const int i1 = 2 * ll;
        const int i2 = (i1 - 1 > 0) ? (i1 - 1) : 0;
        const float e1 = alpha_s[i1];
        const float e2 = alpha_s[i2];
        out[b] = -LN2F * lse2_b2(e1, e2);   // loss = -ln2 * lse_base2
    }
}

extern "C" void kernel_launch(void* const* d_in, const int* in_sizes, int n_in,
                              void* d_out, int out_size, void* d_ws, size_t ws_size,
                              hipStream_t stream) {
    const int*   y_true   = (const int*)d_in[0];
    const float* y_pred   = (const float*)d_in[1];
    const int*   in_len   = (const int*)d_in[2];
    const int*   lab_len  = (const int*)d_in[3];
    float* out = (float*)d_out;

    const int B = in_sizes[0] / Ldim;   // 512
    ctc_fwd_kernel<<<B, 64, 0, stream>>>(y_true, y_pred, in_len, lab_len, out);
}

// Round 5
// 197.484 us; speedup vs baseline: 2.8433x; 2.0403x over previous
//
#include <hip/hip_runtime.h>

#define NEGV (-1e30f)
#define EPSV (1e-7f)
#define LN2F (0.69314718055994531f)

constexpr int Tdim = 1024;
constexpr int Kdim = 128;
constexpr int Ldim = 64;
constexpr int BLK  = 32;    // time-steps per LDS block

// base-2 logsumexp helpers (v_log_f32 / v_exp_f32 are natively base-2)
__device__ __forceinline__ float lse2_b2(float a, float b) {
    float m = fmaxf(a, b);
    return m + __log2f(exp2f(a - m) + exp2f(b - m));
}
__device__ __forceinline__ float lse3_b2(float a, float b, float c) {
    float m = fmaxf(fmaxf(a, b), c);
    return m + __log2f(exp2f(a - m) + exp2f(b - m) + exp2f(c - m));
}

// Async global->LDS DMA: side-effecting intrinsic -> the compiler CANNOT sink
// it to the use point (the failure mode of R1/R2/R4's register rings).
// Global src addr is per-lane; LDS dest is wave-uniform base + lane*4.
__device__ __forceinline__ void dma4(const float* g, float* l) {
    __builtin_amdgcn_global_load_lds(
        (const __attribute__((address_space(1))) unsigned int*)g,
        (__attribute__((address_space(3))) unsigned int*)l,
        4, 0, 0);
}

__global__ __launch_bounds__(64, 1) void ctc_fwd_kernel(
    const int* __restrict__ y_true,      // (B, 64)
    const float* __restrict__ y_pred,    // (B, T, K)
    const int* __restrict__ in_len,      // (B, 1)
    const int* __restrict__ lab_len,     // (B, 1)
    float* __restrict__ out)             // (B, 1)
{
    const int b = blockIdx.x;
    const int lane = threadIdx.x;

    __shared__ float lab_s[2][BLK][64];  // 16 KB: label-prob rows
    __shared__ float blk_s[2][64];       // blank probs; padded to 64 (one 64-lane DMA)

    const float* yp  = y_pred + (size_t)b * Tdim * Kdim;
    const int lab = y_true[b * Ldim + lane];          // labels 0..126 (never blank)
    const int lab_prev = __shfl_up(lab, 1, 64);
    const bool skip = (lane > 0) && (lab != Kdim - 1) && (lab != lab_prev);
    const int steps = in_len[b];                      // 512..1024

    const float* ypl = yp + lab;          // per-lane gather base
    const float* ypb = yp + (Kdim - 1);   // blank base

    // lane i holds alpha2[2i] (a_e), alpha2[2i+1] (a_o); lane 63 also alpha2[128]
    float a_e = (lane == 0) ? 0.0f : NEGV;
    float a_o = NEGV;
    float a_l = NEGV;

    // issue one block's 33 DMA loads: label rows t0..t0+31 + blanks t0..t0+63
    auto issue = [&](int t0, int buf) {
        #pragma unroll
        for (int u = 0; u < BLK; ++u) {
            int t = t0 + u; t = (t > Tdim - 1) ? (Tdim - 1) : t;   // clamp: in-bounds
            dma4(ypl + (size_t)t * Kdim, &lab_s[buf][u][0]);
        }
        int t2 = t0 + lane; t2 = (t2 > Tdim - 1) ? (Tdim - 1) : t2;
        dma4(ypb + (size_t)t2 * Kdim, &blk_s[buf][0]);   // lane j -> blank[t0+j]
    };

    issue(0, 0);                          // prologue: block 0 in flight

    const int steps_full = steps & ~(BLK - 1);   // >= 512

    for (int tb = 0; tb < steps_full; tb += BLK) {
        const int cur = (tb >> 5) & 1;
        // all prior ds_reads done before DMA may overwrite the other buffer
        asm volatile("s_waitcnt lgkmcnt(0)" ::: "memory");
        __builtin_amdgcn_sched_barrier(0);
        issue(tb + BLK, cur ^ 1);         // prefetch next block (33 loads in flight)
        __builtin_amdgcn_sched_barrier(0);
        asm volatile("s_waitcnt vmcnt(33)" ::: "memory");   // current block landed
        __builtin_amdgcn_sched_barrier(0);

        #pragma unroll
        for (int g = 0; g < BLK / 8; ++g) {
            float vl[8], vb[8];
            #pragma unroll
            for (int u = 0; u < 8; ++u) {           // batched LDS reads, static idx
                vl[u] = lab_s[cur][g * 8 + u][lane];
                vb[u] = blk_s[cur][g * 8 + u];      // uniform addr -> broadcast
            }
            #pragma unroll
            for (int u = 0; u < 8; ++u) {
                const float lp_lab = __log2f(vl[u] + EPSV);
                const float lp_b   = __log2f(vb[u] + EPSV);
                float p_o = __shfl_up(a_o, 1, 64);  // alpha2[2i-1]
                p_o = (lane == 0) ? NEGV : p_o;
                const float ne = lp_b   + lse2_b2(a_e, p_o);
                const float no = lp_lab + lse3_b2(a_o, a_e, skip ? p_o : NEGV);
                const float nl = lp_b   + lse2_b2(a_l, a_o);
                a_e = ne; a_o = no; a_l = nl;
            }
        }
    }

    // tail block (<= 31 steps); its data is in buf (steps_full>>5)&1.
    // vmcnt(0) here is also the mandatory final drain: in-flight DMAs must not
    // land after the workgroup's LDS is recycled.
    {
        const int cur = (steps_full >> 5) & 1;
        asm volatile("s_waitcnt vmcnt(0)" ::: "memory");
        __builtin_amdgcn_sched_barrier(0);
        #pragma unroll
        for (int u = 0; u < BLK; ++u) {
            if (steps_full + u < steps) {            // wave-uniform guard
                const float lp_lab = __log2f(lab_s[cur][u][lane] + EPSV);
                const float lp_b   = __log2f(blk_s[cur][u] + EPSV);
                float p_o = __shfl_up(a_o, 1, 64);
                p_o = (lane == 0) ? NEGV : p_o;
                const float ne = lp_b   + lse2_b2(a_e, p_o);
                const float no = lp_lab + lse3_b2(a_o, a_e, skip ? p_o : NEGV);
                const float nl = lp_b   + lse2_b2(a_l, a_o);
                a_e = ne; a_o = no; a_l = nl;
            }
        }
    }

    __shared__ float alpha_s[130];
    alpha_s[2 * lane]     = a_e;
    alpha_s[2 * lane + 1] = a_o;
    if (lane == 63) alpha_s[128] = a_l;
    __syncthreads();

    if (lane == 0) {
        const int ll = lab_len[b];
        const int i1 = 2 * ll;
        const int i2 = (i1 - 1 > 0) ? (i1 - 1) : 0;
        out[b] = -LN2F * lse2_b2(alpha_s[i1], alpha_s[i2]);   // loss = -ln2 * lse_b2
    }
}

extern "C" void kernel_launch(void* const* d_in, const int* in_sizes, int n_in,
                              void* d_out, int out_size, void* d_ws, size_t ws_size,
                              hipStream_t stream) {
    const int*   y_true   = (const int*)d_in[0];
    const float* y_pred   = (const float*)d_in[1];
    const int*   in_len   = (const int*)d_in[2];
    const int*   lab_len  = (const int*)d_in[3];
    float* out = (float*)d_out;

    const int B = in_sizes[0] / Ldim;   // 512
    ctc_fwd_kernel<<<B, 64, 0, stream>>>(y_true, y_pred, in_len, lab_len, out);
}

// Round 13
// 138.373 us; speedup vs baseline: 4.0579x; 1.4272x over previous
//
#include <hip/hip_runtime.h>

#define NEGV (-1e30f)
#define EPSV (1e-7f)
#define LN2F (0.69314718055994531f)

constexpr int Tdim = 1024;
constexpr int Kdim = 128;
constexpr int Ldim = 64;
constexpr int BLK  = 32;    // time-steps per LDS block
constexpr int GRP  = 8;     // steps per LDS-read batch

// Async global->LDS DMA, 16B/lane (side-effecting: compiler cannot sink it).
// SEMANTICS (guide m104/m108): global SOURCE is PER-LANE; LDS dest is
// wave-uniform base + lane*16. Caller must pass g = base + lane*16B.
// R8-R12 passed a uniform source -> all lanes fetched the same 16B and the
// staged buffer was row-head replicas: the bit-identical absmax=128 across
// three different numerics. One 64-lane call = 1024B = 2 rows.
__device__ __forceinline__ void dma16(const float* g, float* l) {
    __builtin_amdgcn_global_load_lds(
        (const __attribute__((address_space(1))) unsigned int*)g,
        (__attribute__((address_space(3))) unsigned int*)l,
        16, 0, 0);
}

// Native HW transcendentals: single v_exp_f32 / v_log_f32 (base-2, ~1 ulp).
__device__ __forceinline__ float hw_exp2(float x) { return __builtin_amdgcn_exp2f(x); }
__device__ __forceinline__ float hw_log2(float x) { return __builtin_amdgcn_logf(x); }

// base-2 logsumexp, log-domain (proven numerics: R1-R5 absmax = 0)
__device__ __forceinline__ float lse2_b2(float a, float b) {
    float m = fmaxf(a, b);
    return m + hw_log2(hw_exp2(a - m) + hw_exp2(b - m));
}
__device__ __forceinline__ float lse3_b2(float a, float b, float c) {
    float m = fmaxf(fmaxf(a, b), c);          // -> v_max3_f32
    return m + hw_log2(hw_exp2(a - m) + hw_exp2(b - m) + hw_exp2(c - m));
}

__global__ __launch_bounds__(64, 1) void ctc_fwd_kernel(
    const int* __restrict__ y_true,      // (B, 64)
    const float* __restrict__ y_pred,    // (B, T, K)
    const int* __restrict__ in_len,      // (B, 1)
    const int* __restrict__ lab_len,     // (B, 1)
    float* __restrict__ out)             // (B, 1)
{
    const int b = blockIdx.x;
    const int lane = threadIdx.x;

    __shared__ float rows[2][BLK][Kdim]; // 32 KB: full prob rows (coalesced DMA)
    __shared__ float alpha_s[130];

    const float* yp  = y_pred + (size_t)b * Tdim * Kdim;
    const int lab = y_true[b * Ldim + lane];          // labels 0..126 (never blank)
    const int lab_prev = __shfl_up(lab, 1, 64);       // once, outside hot loop
    const bool skip = (lane > 0) && (lab != Kdim - 1) && (lab != lab_prev);
    const int steps = in_len[b];                      // 512..1024

    // log2-domain alphas (alpha2 = alpha/ln2).
    // lane i: a_e=alpha2[2i], a_o=alpha2[2i+1]; lane 63 also a_l=alpha2[128]
    float a_e = (lane == 0) ? 0.0f : NEGV;
    float a_o = NEGV;
    float a_l = NEGV;

    // stage rows t0..t0+31: 16 coalesced 1KB DMAs, PER-LANE source = +lane*16B
    auto issue = [&](int t0, int buf) {
        #pragma unroll
        for (int u = 0; u < BLK / 2; ++u) {
            int t = t0 + 2 * u;
            t = (t > Tdim - 2) ? (Tdim - 2) : t;     // clamp pair: in-bounds
            dma16(yp + (size_t)t * Kdim + 4 * lane, &rows[buf][2 * u][0]);
        }
    };

    auto stepfn = [&](float lpl, float lpb) {
        float p_o = __shfl_up(a_o, 1, 64);           // alpha2[2i-1]
        p_o = (lane == 0) ? NEGV : p_o;
        const float ne = lpb + lse2_b2(a_e, p_o);
        const float no = lpl + lse3_b2(a_o, a_e, skip ? p_o : NEGV);
        const float nl = lpb + lse2_b2(a_l, a_o);
        a_e = ne; a_o = no; a_l = nl;
    };

    issue(0, 0);                              // prologue: block 0 in flight (16)

    const int steps_full = steps & ~(BLK - 1);   // >= 512, multiple of BLK

    for (int tb = 0; tb < steps_full; tb += BLK) {
        const int cur = (tb >> 5) & 1;
        asm volatile("s_waitcnt lgkmcnt(0)" ::: "memory");   // reads done before overwrite
        __builtin_amdgcn_sched_barrier(0);
        issue(tb + BLK, cur ^ 1);             // prefetch next block (16 in flight)
        __builtin_amdgcn_sched_barrier(0);
        asm volatile("s_waitcnt vmcnt(16)" ::: "memory");    // current block landed
        __builtin_amdgcn_sched_barrier(0);

        #pragma unroll
        for (int g = 0; g < BLK / GRP; ++g) {
            float lpl[GRP], lpb[GRP];
            #pragma unroll
            for (int u = 0; u < GRP; ++u) {   // batched LDS reads + logs, off-chain
                lpl[u] = hw_log2(rows[cur][g * GRP + u][lab] + EPSV);
                lpb[u] = hw_log2(rows[cur][g * GRP + u][Kdim - 1] + EPSV);
            }
            #pragma unroll
            for (int u = 0; u < GRP; ++u) stepfn(lpl[u], lpb[u]);
        }
    }

    // tail block (<= 31 steps) + mandatory final DMA drain (unconditional)
    {
        const int cur = (steps_full >> 5) & 1;
        asm volatile("s_waitcnt vmcnt(0)" ::: "memory");
        __builtin_amdgcn_sched_barrier(0);
        #pragma unroll
        for (int u = 0; u < BLK; ++u) {
            if (steps_full + u < steps) {      // wave-uniform guard
                const float lpl = hw_log2(rows[cur][u][lab] + EPSV);
                const float lpb = hw_log2(rows[cur][u][Kdim - 1] + EPSV);
                stepfn(lpl, lpb);
            }
        }
    }

    alpha_s[2 * lane]     = a_e;
    alpha_s[2 * lane + 1] = a_o;
    if (lane == 63) alpha_s[128] = a_l;
    __syncthreads();

    if (lane == 0) {
        const int ll = lab_len[b];            // 8..64
        const int i1 = 2 * ll;
        const int i2 = i1 - 1;                // ll >= 8 -> no clamp needed
        out[b] = -LN2F * lse2_b2(alpha_s[i1], alpha_s[i2]);   // -ln2 * lse_b2
    }
}

extern "C" void kernel_launch(void* const* d_in, const int* in_sizes, int n_in,
                              void* d_out, int out_size, void* d_ws, size_t ws_size,
                              hipStream_t stream) {
    const int*   y_true   = (const int*)d_in[0];
    const float* y_pred   = (const float*)d_in[1];
    const int*   in_len   = (const int*)d_in[2];
    const int*   lab_len  = (const int*)d_in[3];
    float* out = (float*)d_out;

    const int B = in_sizes[0] / Ldim;   // 512
    ctc_fwd_kernel<<<B, 64, 0, stream>>>(y_true, y_pred, in_len, lab_len, out);
}

// Round 14
// 123.324 us; speedup vs baseline: 4.5530x; 1.1220x over previous
//
#include <hip/hip_runtime.h>

#define NEGV (-1e30f)
#define EPSV (1e-7f)
#define LN2F (0.69314718055994531f)

constexpr int Tdim = 1024;
constexpr int Kdim = 128;
constexpr int Ldim = 64;
constexpr int BLK  = 32;    // time-steps per LDS block
constexpr int GRP  = 8;     // steps per LDS-read batch

// Async global->LDS DMA, 16B/lane (side-effecting: compiler cannot sink it).
// Global SOURCE is PER-LANE (caller passes base + lane*16B); LDS dest is
// wave-uniform base + lane*16 (m104/m108). One 64-lane call = 1024B = 2 rows.
__device__ __forceinline__ void dma16(const float* g, float* l) {
    __builtin_amdgcn_global_load_lds(
        (const __attribute__((address_space(1))) unsigned int*)g,
        (__attribute__((address_space(3))) unsigned int*)l,
        16, 0, 0);
}

// Native HW transcendentals: single v_exp_f32 / v_log_f32 (base-2, ~1 ulp).
__device__ __forceinline__ float hw_exp2(float x) { return __builtin_amdgcn_exp2f(x); }
__device__ __forceinline__ float hw_log2(float x) { return __builtin_amdgcn_logf(x); }

// Wave shift-up-by-1 via DPP (v_mov_b32_dpp wave_shr:1, ctrl 0x138):
// lane i <- lane i-1 in ONE full-rate VALU op (~4 cy) vs ds_bpermute's
// ~110 cy LDS-pipe latency — the serial chain's dominant element in R13.
// bound_ctrl=false: invalid lane 0 keeps `old` = NEGV (boundary for free).
__device__ __forceinline__ float dpp_shr1(float x, float old) {
    return __int_as_float(__builtin_amdgcn_update_dpp(
        __float_as_int(old), __float_as_int(x), 0x138, 0xF, 0xF, false));
}

// base-2 logsumexp, log-domain (proven numerics: R13 absmax = 0)
__device__ __forceinline__ float lse2_b2(float a, float b) {
    float m = fmaxf(a, b);
    return m + hw_log2(hw_exp2(a - m) + hw_exp2(b - m));
}
__device__ __forceinline__ float lse3_b2(float a, float b, float c) {
    float m = fmaxf(fmaxf(a, b), c);          // -> v_max3_f32
    return m + hw_log2(hw_exp2(a - m) + hw_exp2(b - m) + hw_exp2(c - m));
}

__global__ __launch_bounds__(64, 1) void ctc_fwd_kernel(
    const int* __restrict__ y_true,      // (B, 64)
    const float* __restrict__ y_pred,    // (B, T, K)
    const int* __restrict__ in_len,      // (B, 1)
    const int* __restrict__ lab_len,     // (B, 1)
    float* __restrict__ out)             // (B, 1)
{
    const int b = blockIdx.x;
    const int lane = threadIdx.x;

    __shared__ float rows[2][BLK][Kdim]; // 32 KB: full prob rows (coalesced DMA)
    __shared__ float alpha_s[130];

    const float* yp  = y_pred + (size_t)b * Tdim * Kdim;
    const int lab = y_true[b * Ldim + lane];          // labels 0..126 (never blank)
    const int lab_prev = __shfl_up(lab, 1, 64);       // once, outside hot loop
    const bool skip = (lane > 0) && (lab != Kdim - 1) && (lab != lab_prev);
    const int steps = in_len[b];                      // 512..1024

    // log2-domain alphas (alpha2 = alpha/ln2).
    // lane i: a_e=alpha2[2i], a_o=alpha2[2i+1]; lane 63 also a_l=alpha2[128]
    float a_e = (lane == 0) ? 0.0f : NEGV;
    float a_o = NEGV;
    float a_l = NEGV;

    // stage rows t0..t0+31: 16 coalesced 1KB DMAs, PER-LANE source = +lane*16B
    auto issue = [&](int t0, int buf) {
        #pragma unroll
        for (int u = 0; u < BLK / 2; ++u) {
            int t = t0 + 2 * u;
            t = (t > Tdim - 2) ? (Tdim - 2) : t;     // clamp pair: in-bounds
            dma16(yp + (size_t)t * Kdim + 4 * lane, &rows[buf][2 * u][0]);
        }
    };

    auto stepfn = [&](float lpl, float lpb) {
        const float p_o = dpp_shr1(a_o, NEGV);       // alpha2[2i-1]; lane0 -> NEGV
        const float ne = lpb + lse2_b2(a_e, p_o);
        const float no = lpl + lse3_b2(a_o, a_e, skip ? p_o : NEGV);
        const float nl = lpb + lse2_b2(a_l, a_o);
        a_e = ne; a_o = no; a_l = nl;
    };

    issue(0, 0);                              // prologue: block 0 in flight (16)

    const int steps_full = steps & ~(BLK - 1);   // >= 512, multiple of BLK

    for (int tb = 0; tb < steps_full; tb += BLK) {
        const int cur = (tb >> 5) & 1;
        asm volatile("s_waitcnt lgkmcnt(0)" ::: "memory");   // reads done before overwrite
        __builtin_amdgcn_sched_barrier(0);
        issue(tb + BLK, cur ^ 1);             // prefetch next block (16 in flight)
        __builtin_amdgcn_sched_barrier(0);
        asm volatile("s_waitcnt vmcnt(16)" ::: "memory");    // current block landed
        __builtin_amdgcn_sched_barrier(0);

        #pragma unroll
        for (int g = 0; g < BLK / GRP; ++g) {
            float lpl[GRP], lpb[GRP];
            #pragma unroll
            for (int u = 0; u < GRP; ++u) {   // batched LDS reads + logs, off-chain
                lpl[u] = hw_log2(rows[cur][g * GRP + u][lab] + EPSV);
                lpb[u] = hw_log2(rows[cur][g * GRP + u][Kdim - 1] + EPSV);
            }
            #pragma unroll
            for (int u = 0; u < GRP; ++u) stepfn(lpl[u], lpb[u]);
        }
    }

    // tail block (<= 31 steps) + mandatory final DMA drain (unconditional)
    {
        const int cur = (steps_full >> 5) & 1;
        asm volatile("s_waitcnt vmcnt(0)" ::: "memory");
        __builtin_amdgcn_sched_barrier(0);
        #pragma unroll
        for (int u = 0; u < BLK; ++u) {
            if (steps_full + u < steps) {      // wave-uniform guard
                const float lpl = hw_log2(rows[cur][u][lab] + EPSV);
                const float lpb = hw_log2(rows[cur][u][Kdim - 1] + EPSV);
                stepfn(lpl, lpb);
            }
        }
    }

    alpha_s[2 * lane]     = a_e;
    alpha_s[2 * lane + 1] = a_o;
    if (lane == 63) alpha_s[128] = a_l;
    __syncthreads();

    if (lane == 0) {
        const int ll = lab_len[b];            // 8..64
        const int i1 = 2 * ll;
        const int i2 = i1 - 1;                // ll >= 8 -> no clamp needed
        out[b] = -LN2F * lse2_b2(alpha_s[i1], alpha_s[i2]);   // -ln2 * lse_b2
    }
}

extern "C" void kernel_launch(void* const* d_in, const int* in_sizes, int n_in,
                              void* d_out, int out_size, void* d_ws, size_t ws_size,
                              hipStream_t stream) {
    const int*   y_true   = (const int*)d_in[0];
    const float* y_pred   = (const float*)d_in[1];
    const int*   in_len   = (const int*)d_in[2];
    const int*   lab_len  = (const int*)d_in[3];
    float* out = (float*)d_out;

    const int B = in_sizes[0] / Ldim;   // 512
    ctc_fwd_kernel<<<B, 64, 0, stream>>>(y_true, y_pred, in_len, lab_len, out);
}

// Round 15
// 110.794 us; speedup vs baseline: 5.0679x; 1.1131x over previous
//
#include <hip/hip_runtime.h>

#define EPSV (1e-7f)
#define LN2F (0.69314718055994531f)
#define NEGK (-(1 << 29))   // frame sentinel for empty (value==0) states

constexpr int Tdim = 1024;
constexpr int Kdim = 128;
constexpr int Ldim = 64;
constexpr int BLK  = 32;    // time-steps per LDS block
constexpr int GRP  = 8;     // steps per LDS-read batch

// Async global->LDS DMA, 16B/lane. PER-LANE global source (base + lane*16B),
// wave-uniform LDS dest (m104/m108). One 64-lane call = 1024B = 2 rows.
__device__ __forceinline__ void dma16(const float* g, float* l) {
    __builtin_amdgcn_global_load_lds(
        (const __attribute__((address_space(1))) unsigned int*)g,
        (__attribute__((address_space(3))) unsigned int*)l,
        16, 0, 0);
}

// Wave shift-up-by-1 via DPP (wave_shr:1, ctrl 0x138), proven in R14.
// bound_ctrl=false: lane 0 keeps `old`.
__device__ __forceinline__ float dpp_shr1_f(float x, float old) {
    return __int_as_float(__builtin_amdgcn_update_dpp(
        __float_as_int(old), __float_as_int(x), 0x138, 0xF, 0xF, false));
}
__device__ __forceinline__ int dpp_shr1_i(int x, int old) {
    return __builtin_amdgcn_update_dpp(old, x, 0x138, 0xF, 0xF, false);
}

__device__ __forceinline__ float hw_log2(float x) { return __builtin_amdgcn_logf(x); }
__device__ __forceinline__ int imax(int a, int b) { return a > b ? a : b; }

__global__ __launch_bounds__(64, 1) void ctc_fwd_kernel(
    const int* __restrict__ y_true,      // (B, 64)
    const float* __restrict__ y_pred,    // (B, T, K)
    const int* __restrict__ in_len,      // (B, 1)
    const int* __restrict__ lab_len,     // (B, 1)
    float* __restrict__ out)             // (B, 1)
{
    const int b = blockIdx.x;
    const int lane = threadIdx.x;

    __shared__ float rows[2][BLK][Kdim]; // 32 KB: full prob rows (coalesced DMA)
    __shared__ float alpha_s[130];
    __shared__ int   ks_s[130];

    const float* yp  = y_pred + (size_t)b * Tdim * Kdim;
    const int lab = y_true[b * Ldim + lane];          // labels 0..126 (never blank)
    const int lab_prev = __shfl_up(lab, 1, 64);       // once, outside hot loop
    const bool skip = (lane > 0) && (lab != Kdim - 1) && (lab != lab_prev);
    const int steps = in_len[b];                      // 512..1024

    // LINEAR domain, PER-STATE extended exponent: true alpha = value * 2^frame.
    // Empty state: value==0, frame==NEGK (so plain max() picks real frames).
    // All shifts into the mix frame are <= 0 -> v_ldexp underflow-saturates,
    // which is exactly logsumexp-style addend truncation (ref does the same
    // at 2^-126 relative via exp underflow). ZERO transcendentals per step.
    float a_e = (lane == 0) ? 1.0f : 0.0f;
    float a_o = 0.0f;
    float a_l = 0.0f;
    int   k_e = (lane == 0) ? 0 : NEGK;
    int   k_o = NEGK;
    int   k_l = NEGK;

    // stage rows t0..t0+31: 16 coalesced 1KB DMAs, PER-LANE source = +lane*16B
    auto issue = [&](int t0, int buf) {
        #pragma unroll
        for (int u = 0; u < BLK / 2; ++u) {
            int t = t0 + 2 * u;
            t = (t > Tdim - 2) ? (Tdim - 2) : t;     // clamp pair: in-bounds
            dma16(yp + (size_t)t * Kdim + 4 * lane, &rows[buf][2 * u][0]);
        }
    };

    // One DP step: ~40 full-rate VALU, no transcendentals.
    auto stepfn = [&](float pl, float pb) {
        const float p_o = dpp_shr1_f(a_o, 0.0f);     // neighbor a_o; lane0 -> 0
        const int   pk  = dpp_shr1_i(k_o, NEGK);     // its frame; lane0 -> NEGK
        const int   pk3 = skip ? pk  : NEGK;         // skip-masked (frame AND value)
        const float p3v = skip ? p_o : 0.0f;

        const int kw1 = imax(k_e, pk);
        const float ne = pb * (ldexpf(a_e, k_e - kw1) + ldexpf(p_o, pk - kw1));

        const int kw2 = imax(imax(k_o, k_e), pk3);
        const float no = pl * (ldexpf(a_o, k_o - kw2) +
                               ldexpf(a_e, k_e - kw2) +
                               ldexpf(p3v, pk3 - kw2));

        const int kw3 = imax(k_l, k_o);
        const float nl = pb * (ldexpf(a_l, k_l - kw3) + ldexpf(a_o, k_o - kw3));

        // zero-result guard: a 0 value must carry the NEGK frame, otherwise a
        // dead state's large frame would suppress live content in later mixes
        a_e = ne; k_e = (ne == 0.0f) ? NEGK : kw1;
        a_o = no; k_o = (no == 0.0f) ? NEGK : kw2;
        a_l = nl; k_l = (nl == 0.0f) ? NEGK : kw3;
    };

    // per-state renorm into [1,2) (exact power-of-2), every 4 steps:
    // bounds the inter-renorm drift to >= 2^-92 -> worst-case truncation
    // margin ~57 bits, utterly negligible at threshold 103.
    auto renorm1 = [](float& v, int& k) {
        const int mb = (__float_as_int(v) >> 23) & 0xff;
        if (mb != 0) { k += mb - 127; v *= __int_as_float((254 - mb) << 23); }
    };
    auto renorm = [&]() { renorm1(a_e, k_e); renorm1(a_o, k_o); renorm1(a_l, k_l); };

    issue(0, 0);                              // prologue: block 0 in flight (16)

    const int steps_full = steps & ~(BLK - 1);   // >= 512, multiple of BLK

    for (int tb = 0; tb < steps_full; tb += BLK) {
        const int cur = (tb >> 5) & 1;
        asm volatile("s_waitcnt lgkmcnt(0)" ::: "memory");   // reads done before overwrite
        __builtin_amdgcn_sched_barrier(0);
        issue(tb + BLK, cur ^ 1);             // prefetch next block (16 in flight)
        __builtin_amdgcn_sched_barrier(0);
        asm volatile("s_waitcnt vmcnt(16)" ::: "memory");    // current block landed
        __builtin_amdgcn_sched_barrier(0);

        #pragma unroll
        for (int g = 0; g < BLK / GRP; ++g) {
            float vl[GRP], vb[GRP];
            #pragma unroll
            for (int u = 0; u < GRP; ++u) {   // batched LDS reads, off-chain
                vl[u] = rows[cur][g * GRP + u][lab] + EPSV;      // per-lane gather
                vb[u] = rows[cur][g * GRP + u][Kdim - 1] + EPSV; // uniform bcast
            }
            #pragma unroll
            for (int u = 0; u < GRP; ++u) {
                stepfn(vl[u], vb[u]);
                if ((u & 3) == 3) renorm();   // every 4 steps
            }
        }
    }

    // tail block (<= 31 steps) + mandatory final DMA drain (unconditional)
    {
        const int cur = (steps_full >> 5) & 1;
        asm volatile("s_waitcnt vmcnt(0)" ::: "memory");
        __builtin_amdgcn_sched_barrier(0);
        #pragma unroll
        for (int u = 0; u < BLK; ++u) {
            if (steps_full + u < steps) {      // wave-uniform guard
                stepfn(rows[cur][u][lab] + EPSV, rows[cur][u][Kdim - 1] + EPSV);
                if ((u & 3) == 3) renorm();
            }
        }
    }

    alpha_s[2 * lane]     = a_e;
    alpha_s[2 * lane + 1] = a_o;
    ks_s[2 * lane]        = k_e;
    ks_s[2 * lane + 1]    = k_o;
    if (lane == 63) { alpha_s[128] = a_l; ks_s[128] = k_l; }
    __syncthreads();

    if (lane == 0) {
        const int ll = lab_len[b];            // 8..64
        const int i1 = 2 * ll;
        const int i2 = i1 - 1;                // ll >= 8 -> no clamp needed
        const float v1 = alpha_s[i1], v2 = alpha_s[i2];
        const int   k1 = ks_s[i1],   k2 = ks_s[i2];
        const int   K  = imax(k1, k2);        // at least one state is nonzero
        const float s  = ldexpf(v1, k1 - K) + ldexpf(v2, k2 - K);
        out[b] = -LN2F * (hw_log2(s) + (float)K);
    }
}

extern "C" void kernel_launch(void* const* d_in, const int* in_sizes, int n_in,
                              void* d_out, int out_size, void* d_ws, size_t ws_size,
                              hipStream_t stream) {
    const int*   y_true   = (const int*)d_in[0];
    const float* y_pred   = (const float*)d_in[1];
    const int*   in_len   = (const int*)d_in[2];
    const int*   lab_len  = (const int*)d_in[3];
    float* out = (float*)d_out;

    const int B = in_sizes[0] / Ldim;   // 512
    ctc_fwd_kernel<<<B, 64, 0, stream>>>(y_true, y_pred, in_len, lab_len, out);
}

// Round 17
// 109.885 us; speedup vs baseline: 5.1099x; 1.0083x over previous
//
#include <hip/hip_runtime.h>

#define EPSV (1e-7f)
#define LN2F (0.69314718055994531f)
#define NEGK (-(1 << 29))   // frame sentinel for empty (value==0) states

constexpr int Tdim = 1024;
constexpr int Kdim = 128;
constexpr int Ldim = 64;
constexpr int BLK  = 32;    // time-steps per LDS block

// Async global->LDS DMA, 16B/lane. PER-LANE global source (base + lane*16B),
// wave-uniform LDS dest (m104/m108). One 64-lane call = 1024B = 2 rows.
__device__ __forceinline__ void dma16(const float* g, float* l) {
    __builtin_amdgcn_global_load_lds(
        (const __attribute__((address_space(1))) unsigned int*)g,
        (__attribute__((address_space(3))) unsigned int*)l,
        16, 0, 0);
}

// Wave shift-up-by-1 via DPP (wave_shr:1, ctrl 0x138), proven R14/R15.
// bound_ctrl=false: lane 0 keeps `old`.
__device__ __forceinline__ float dpp_shr1_f(float x, float old) {
    return __int_as_float(__builtin_amdgcn_update_dpp(
        __float_as_int(old), __float_as_int(x), 0x138, 0xF, 0xF, false));
}
__device__ __forceinline__ int dpp_shr1_i(int x, int old) {
    return __builtin_amdgcn_update_dpp(old, x, 0x138, 0xF, 0xF, false);
}

__device__ __forceinline__ float hw_log2(float x) { return __builtin_amdgcn_logf(x); }
__device__ __forceinline__ int imax(int a, int b) { return a > b ? a : b; }

__global__ __launch_bounds__(64, 1) void ctc_fwd_kernel(
    const int* __restrict__ y_true,      // (B, 64)
    const float* __restrict__ y_pred,    // (B, T, K)
    const int* __restrict__ in_len,      // (B, 1)
    const int* __restrict__ lab_len,     // (B, 1)
    float* __restrict__ out)             // (B, 1)
{
    const int b = blockIdx.x;
    const int lane = threadIdx.x;

    __shared__ float rows[2][BLK][Kdim]; // 32 KB: full prob rows (coalesced DMA)
    __shared__ float alpha_s[130];
    __shared__ int   ks_s[130];

    const float* yp  = y_pred + (size_t)b * Tdim * Kdim;
    const int lab = y_true[b * Ldim + lane];          // labels 0..126 (never blank)
    const int lab_prev = __shfl_up(lab, 1, 64);       // once, outside hot loop
    const bool skip = (lane > 0) && (lab != Kdim - 1) && (lab != lab_prev);
    const int steps = in_len[b];                      // 512..1024

    // LINEAR domain, PER-STATE extended exponent: true alpha = value * 2^frame.
    // Empty state: value==0, frame==NEGK -> plain max() picks real frames and
    // zero-valued states can never suppress live content (R16's failure mode).
    // All shifts into the mix frame are <= 0 -> ldexp underflow-saturates =
    // logsumexp-style truncation relative to the SAME state's dominant term
    // (ref does the same at 2^-126 relative via exp underflow).
    // PROVEN: R15 absmax = 0.0.
    float a_e = (lane == 0) ? 1.0f : 0.0f;
    float a_o = 0.0f;
    float a_l = 0.0f;
    int   k_e = (lane == 0) ? 0 : NEGK;
    int   k_o = NEGK;
    int   k_l = NEGK;

    // stage rows t0..t0+31: 16 coalesced 1KB DMAs, PER-LANE source = +lane*16B
    auto issue = [&](int t0, int buf) {
        #pragma unroll
        for (int u = 0; u < BLK / 2; ++u) {
            int t = t0 + 2 * u;
            t = (t > Tdim - 2) ? (Tdim - 2) : t;     // clamp pair: in-bounds
            dma16(yp + (size_t)t * Kdim + 4 * lane, &rows[buf][2 * u][0]);
        }
    };

    // One DP step: ~40 full-rate VALU, no transcendentals. (R15-identical)
    auto stepfn = [&](float pl, float pb) {
        const float p_o = dpp_shr1_f(a_o, 0.0f);     // neighbor a_o; lane0 -> 0
        const int   pk  = dpp_shr1_i(k_o, NEGK);     // its frame; lane0 -> NEGK
        const int   pk3 = skip ? pk  : NEGK;         // skip-masked (frame AND value)
        const float p3v = skip ? p_o : 0.0f;

        const int kw1 = imax(k_e, pk);
        const float ne = pb * (ldexpf(a_e, k_e - kw1) + ldexpf(p_o, pk - kw1));

        const int kw2 = imax(imax(k_o, k_e), pk3);
        const float no = pl * (ldexpf(a_o, k_o - kw2) +
                               ldexpf(a_e, k_e - kw2) +
                               ldexpf(p3v, pk3 - kw2));

        const int kw3 = imax(k_l, k_o);
        const float nl = pb * (ldexpf(a_l, k_l - kw3) + ldexpf(a_o, k_o - kw3));

        // zero-result guard: a 0 value must carry the NEGK frame, otherwise a
        // dead state's large frame would suppress live content in later mixes
        a_e = ne; k_e = (ne == 0.0f) ? NEGK : kw1;
        a_o = no; k_o = (no == 0.0f) ? NEGK : kw2;
        a_l = nl; k_l = (nl == 0.0f) ? NEGK : kw3;
    };

    // per-state renorm into [1,2) (exact power-of-2), every 4 steps
    auto renorm1 = [](float& v, int& k) {
        const int mb = (__float_as_int(v) >> 23) & 0xff;
        if (mb != 0) { k += mb - 127; v *= __int_as_float((254 - mb) << 23); }
    };
    auto renorm = [&]() { renorm1(a_e, k_e); renorm1(a_o, k_o); renorm1(a_l, k_l); };

    issue(0, 0);                              // prologue: block 0 in flight (16)

    const int steps_full = steps & ~(BLK - 1);   // >= 512, multiple of BLK

    for (int tb = 0; tb < steps_full; tb += BLK) {
        const int cur = (tb >> 5) & 1;
        asm volatile("s_waitcnt lgkmcnt(0)" ::: "memory");   // reads done before overwrite
        __builtin_amdgcn_sched_barrier(0);
        issue(tb + BLK, cur ^ 1);             // prefetch next block (16 in flight)
        __builtin_amdgcn_sched_barrier(0);
        asm volatile("s_waitcnt vmcnt(16)" ::: "memory");    // current block landed
        __builtin_amdgcn_sched_barrier(0);

        // burst-read the whole block into registers (static idx after unroll):
        // LDS latency fully decoupled from the serial chain (R16's good half).
        float vl[BLK], vb[BLK];
        #pragma unroll
        for (int u = 0; u < BLK; ++u) {
            vl[u] = rows[cur][u][lab] + EPSV;        // per-lane gather
            vb[u] = rows[cur][u][Kdim - 1] + EPSV;   // uniform -> broadcast
        }
        #pragma unroll
        for (int u = 0; u < BLK; ++u) {
            stepfn(vl[u], vb[u]);
            if ((u & 3) == 3) renorm();              // every 4 steps
        }
    }

    // tail block (<= 31 steps) + mandatory final DMA drain (unconditional)
    {
        const int cur = (steps_full >> 5) & 1;
        asm volatile("s_waitcnt vmcnt(0)" ::: "memory");
        __builtin_amdgcn_sched_barrier(0);
        float vl[BLK], vb[BLK];
        #pragma unroll
        for (int u = 0; u < BLK; ++u) {              // staged: reads unconditional
            vl[u] = rows[cur][u][lab] + EPSV;
            vb[u] = rows[cur][u][Kdim - 1] + EPSV;
        }
        #pragma unroll
        for (int u = 0; u < BLK; ++u) {
            if (steps_full + u < steps) {            // wave-uniform guard
                stepfn(vl[u], vb[u]);
                if ((u & 3) == 3) renorm();
            }
        }
    }

    alpha_s[2 * lane]     = a_e;
    alpha_s[2 * lane + 1] = a_o;
    ks_s[2 * lane]        = k_e;
    ks_s[2 * lane + 1]    = k_o;
    if (lane == 63) { alpha_s[128] = a_l; ks_s[128] = k_l; }
    __syncthreads();

    if (lane == 0) {
        const int ll = lab_len[b];            // 8..64
        const int i1 = 2 * ll;
        const int i2 = i1 - 1;                // ll >= 8 -> no clamp needed
        const float v1 = alpha_s[i1], v2 = alpha_s[i2];
        const int   k1 = ks_s[i1],   k2 = ks_s[i2];
        const int   K  = imax(k1, k2);        // at least one state is nonzero
        const float s  = ldexpf(v1, k1 - K) + ldexpf(v2, k2 - K);
        out[b] = -LN2F * (hw_log2(s) + (float)K);
    }
}

extern "C" void kernel_launch(void* const* d_in, const int* in_sizes, int n_in,
                              void* d_out, int out_size, void* d_ws, size_t ws_size,
                              hipStream_t stream) {
    const int*   y_true   = (const int*)d_in[0];
    const float* y_pred   = (const float*)d_in[1];
    const int*   in_len   = (const int*)d_in[2];
    const int*   lab_len  = (const int*)d_in[3];
    float* out = (float*)d_out;

    const int B = in_sizes[0] / Ldim;   // 512
    ctc_fwd_kernel<<<B, 64, 0, stream>>>(y_true, y_pred, in_len, lab_len, out);
}

// Round 18
// 67.538 us; speedup vs baseline: 8.3138x; 1.6270x over previous
//
#include <hip/hip_runtime.h>

#define EPSV (1e-7f)
#define LN2F (0.69314718055994531f)
#define NEGK (-(1 << 29))   // frame sentinel for empty (value==0) states (warm-up)

constexpr int Tdim = 1024;
constexpr int Kdim = 128;
constexpr int Ldim = 64;
constexpr int BLK  = 32;    // time-steps per LDS block
constexpr int WARM = 96;    // warm-up steps (front crosses lattice by t=65)
constexpr int CENB = 175;   // renorm target biased exponent (lane max ~2^48)

// Async global->LDS DMA, 16B/lane. PER-LANE global source (base + lane*16B),
// wave-uniform LDS dest (m104/m108). One 64-lane call = 1024B = 2 rows.
__device__ __forceinline__ void dma16(const float* g, float* l) {
    __builtin_amdgcn_global_load_lds(
        (const __attribute__((address_space(1))) unsigned int*)g,
        (__attribute__((address_space(3))) unsigned int*)l,
        16, 0, 0);
}

// Wave shift-up-by-1 via DPP (wave_shr:1, ctrl 0x138), proven R14-R17.
// bound_ctrl=false: lane 0 keeps `old`.
__device__ __forceinline__ float dpp_shr1_f(float x, float old) {
    return __int_as_float(__builtin_amdgcn_update_dpp(
        __float_as_int(old), __float_as_int(x), 0x138, 0xF, 0xF, false));
}
__device__ __forceinline__ int dpp_shr1_i(int x, int old) {
    return __builtin_amdgcn_update_dpp(old, x, 0x138, 0xF, 0xF, false);
}

__device__ __forceinline__ float hw_log2(float x) { return __builtin_amdgcn_logf(x); }
__device__ __forceinline__ int imax(int a, int b) { return a > b ? a : b; }

__global__ __launch_bounds__(64, 1) void ctc_fwd_kernel(
    const int* __restrict__ y_true,      // (B, 64)
    const float* __restrict__ y_pred,    // (B, T, K)
    const int* __restrict__ in_len,      // (B, 1)
    const int* __restrict__ lab_len,     // (B, 1)
    float* __restrict__ out)             // (B, 1)
{
    const int b = blockIdx.x;
    const int lane = threadIdx.x;

    __shared__ float rows[2][BLK][Kdim]; // 32 KB: full prob rows (coalesced DMA)
    __shared__ float alpha_s[130];
    __shared__ int   ks_s[130];

    const float* yp  = y_pred + (size_t)b * Tdim * Kdim;
    const int lab = y_true[b * Ldim + lane];          // labels 0..126 (never blank)
    const int lab_prev = __shfl_up(lab, 1, 64);       // once, outside hot loop
    const bool skip = (lane > 0) && (lab != Kdim - 1) && (lab != lab_prev);
    const int steps = in_len[b];                      // 512..1024

    // ---- WARM-UP state: per-STATE extended exponent (R15/R17 proven) ----
    float a_e = (lane == 0) ? 1.0f : 0.0f;
    float a_o = 0.0f;
    float a_l = 0.0f;
    int   k_e = (lane == 0) ? 0 : NEGK;
    int   k_o = NEGK;
    int   k_l = NEGK;

    auto issue = [&](int t0, int buf) {
        #pragma unroll
        for (int u = 0; u < BLK / 2; ++u) {
            int t = t0 + 2 * u;
            t = (t > Tdim - 2) ? (Tdim - 2) : t;     // clamp pair: in-bounds
            dma16(yp + (size_t)t * Kdim + 4 * lane, &rows[buf][2 * u][0]);
        }
    };

    // R17 slow step (proven absmax 0): per-state frames + zero-guards.
    auto step_slow = [&](float pl, float pb) {
        const float p_o = dpp_shr1_f(a_o, 0.0f);
        const int   pk  = dpp_shr1_i(k_o, NEGK);
        const int   pk3 = skip ? pk  : NEGK;
        const float p3v = skip ? p_o : 0.0f;
        const int kw1 = imax(k_e, pk);
        const float ne = pb * (ldexpf(a_e, k_e - kw1) + ldexpf(p_o, pk - kw1));
        const int kw2 = imax(imax(k_o, k_e), pk3);
        const float no = pl * (ldexpf(a_o, k_o - kw2) +
                               ldexpf(a_e, k_e - kw2) +
                               ldexpf(p3v, pk3 - kw2));
        const int kw3 = imax(k_l, k_o);
        const float nl = pb * (ldexpf(a_l, k_l - kw3) + ldexpf(a_o, k_o - kw3));
        a_e = ne; k_e = (ne == 0.0f) ? NEGK : kw1;
        a_o = no; k_o = (no == 0.0f) ? NEGK : kw2;
        a_l = nl; k_l = (nl == 0.0f) ? NEGK : kw3;
    };
    auto renorm1 = [](float& v, int& k) {
        const int mb = (__float_as_int(v) >> 23) & 0xff;
        if (mb != 0) { k += mb - 127; v *= __int_as_float((254 - mb) << 23); }
    };
    auto renorm_slow = [&]() { renorm1(a_e, k_e); renorm1(a_o, k_o); renorm1(a_l, k_l); };

    issue(0, 0);                              // prologue: block 0 in flight (16)

    const int steps_full = steps & ~(BLK - 1);   // >= 512, multiple of BLK

    // ---- warm-up: first WARM steps with the proven slow path ----
    for (int tb = 0; tb < WARM; tb += BLK) {
        const int cur = (tb >> 5) & 1;
        asm volatile("s_waitcnt lgkmcnt(0)" ::: "memory");
        __builtin_amdgcn_sched_barrier(0);
        issue(tb + BLK, cur ^ 1);
        __builtin_amdgcn_sched_barrier(0);
        asm volatile("s_waitcnt vmcnt(16)" ::: "memory");
        __builtin_amdgcn_sched_barrier(0);
        float vl[BLK], vb[BLK];
        #pragma unroll
        for (int u = 0; u < BLK; ++u) {
            vl[u] = rows[cur][u][lab] + EPSV;
            vb[u] = rows[cur][u][Kdim - 1] + EPSV;
        }
        #pragma unroll
        for (int u = 0; u < BLK; ++u) {
            step_slow(vl[u], vb[u]);
            if ((u & 3) == 3) renorm_slow();
        }
    }

    // ---- convert to per-LANE frozen frame, lane max centered at 2^48 ----
    // Post-warm-up every state is > 0 (front crossed by t=65; pb >= eps keeps
    // the max-frame term of each mix alive). Sibling flush at >105 bits below
    // lane max ~ e^-73 relative: same truncation class as ref's exp underflow.
    int kk = imax(imax(k_e, k_o), k_l);
    a_e = ldexpf(a_e, k_e - kk + 48);
    a_o = ldexpf(a_o, k_o - kk + 48);
    a_l = ldexpf(a_l, k_l - kk + 48);
    kk -= 48;
    int d = dpp_shr1_i(kk, 0) - kk;           // cross-lane frame delta (frozen)

    // fast renorm: re-center lane max to [2^48, 2^49), update kk and d.
    auto renorm_fast = [&]() {
        const float m = fmaxf(fmaxf(a_e, a_o), a_l);     // > 0, normal range
        const int mb = __float_as_int(m) >> 23;
        const float sc = __int_as_float((127 + CENB - mb) << 23);  // 2^(CENB-mb)
        kk += mb - CENB;
        a_e *= sc; a_o *= sc; a_l *= sc;
        d = dpp_shr1_i(kk, 0) - kk;            // lane0: d=-kk, unused (p_o=0)
    };
    // fast step: pure f32, frames frozen. ~10 VALU.
    auto step_fast = [&](float pl, float pb) {
        const float p_o  = dpp_shr1_f(a_o, 0.0f);        // lane0 -> 0
        const float p_a  = ldexpf(p_o, d);               // align neighbor frame
        const float p_s  = skip ? p_a : 0.0f;
        const float ne = pb * (a_e + p_a);
        const float no = pl * (a_o + (a_e + p_s));
        const float nl = pb * (a_l + a_o);
        a_e = ne; a_o = no; a_l = nl;
    };

    // ---- main fast loop ----
    for (int tb = WARM; tb < steps_full; tb += BLK) {
        const int cur = (tb >> 5) & 1;
        asm volatile("s_waitcnt lgkmcnt(0)" ::: "memory");
        __builtin_amdgcn_sched_barrier(0);
        issue(tb + BLK, cur ^ 1);
        __builtin_amdgcn_sched_barrier(0);
        asm volatile("s_waitcnt vmcnt(16)" ::: "memory");
        __builtin_amdgcn_sched_barrier(0);
        float vl[BLK], vb[BLK];
        #pragma unroll
        for (int u = 0; u < BLK; ++u) {
            vl[u] = rows[cur][u][lab] + EPSV;
            vb[u] = rows[cur][u][Kdim - 1] + EPSV;
        }
        #pragma unroll
        for (int u = 0; u < BLK; ++u) {
            if ((u & 3) == 0) renorm_fast();   // group head: re-center + d
            step_fast(vl[u], vb[u]);
        }
    }

    // ---- tail block (<= 31 steps) + mandatory final DMA drain ----
    {
        const int cur = (steps_full >> 5) & 1;
        asm volatile("s_waitcnt vmcnt(0)" ::: "memory");
        __builtin_amdgcn_sched_barrier(0);
        float vl[BLK], vb[BLK];
        #pragma unroll
        for (int u = 0; u < BLK; ++u) {
            vl[u] = rows[cur][u][lab] + EPSV;
            vb[u] = rows[cur][u][Kdim - 1] + EPSV;
        }
        #pragma unroll
        for (int u = 0; u < BLK; ++u) {
            if (steps_full + u < steps) {      // wave-uniform guard
                if ((u & 3) == 0) renorm_fast();
                step_fast(vl[u], vb[u]);
            }
        }
    }

    alpha_s[2 * lane]     = a_e;
    alpha_s[2 * lane + 1] = a_o;
    ks_s[2 * lane]        = kk;
    ks_s[2 * lane + 1]    = kk;
    if (lane == 63) { alpha_s[128] = a_l; ks_s[128] = kk; }
    __syncthreads();

    if (lane == 0) {
        const int ll = lab_len[b];            // 8..64
        const int i1 = 2 * ll;
        const int i2 = i1 - 1;                // ll >= 8 -> no clamp needed
        const float v1 = alpha_s[i1], v2 = alpha_s[i2];
        const int   k1 = ks_s[i1],   k2 = ks_s[i2];
        const int   K  = imax(k1, k2);
        const float s  = ldexpf(v1, k1 - K) + ldexpf(v2, k2 - K);
        out[b] = -LN2F * (hw_log2(s) + (float)K);
    }
}

extern "C" void kernel_launch(void* const* d_in, const int* in_sizes, int n_in,
                              void* d_out, int out_size, void* d_ws, size_t ws_size,
                              hipStream_t stream) {
    const int*   y_true   = (const int*)d_in[0];
    const float* y_pred   = (const float*)d_in[1];
    const int*   in_len   = (const int*)d_in[2];
    const int*   lab_len  = (const int*)d_in[3];
    float* out = (float*)d_out;

    const int B = in_sizes[0] / Ldim;   // 512
    ctc_fwd_kernel<<<B, 64, 0, stream>>>(y_true, y_pred, in_len, lab_len, out);
}